// Round 1
// baseline (261.587 us; speedup 1.0000x reference)
//
#include <hip/hip_runtime.h>
#include <hip/hip_bf16.h>

#pragma clang fp contract(off)

#define NN   230400   // H*W*A
#define NK   128      // gt boxes
#define HW_  25600    // H*W
#define NA   9
#define NBLK 900      // NN/256

// ---- scalar slots in ws ----
enum { S_CNT_FG=0, S_CNT_BG, S_FG_ACTIVE, S_FG_BIN, S_FG_REM, S_FG_TH, S_NFG_FINAL,
       S_BG_ACTIVE, S_BG_BIN, S_BG_REM, S_BG_TH, S_BG_K, S_NUM_EX };

__device__ __forceinline__ unsigned encf(float f) {
    unsigned u = __float_as_uint(f);
    return (u & 0x80000000u) ? ~u : (u | 0x80000000u);
}
__device__ __forceinline__ float decf(unsigned e) {
    unsigned u = (e & 0x80000000u) ? (e & 0x7FFFFFFFu) : ~e;
    return __uint_as_float(u);
}

__global__ __launch_bounds__(256) void k_init(unsigned* __restrict__ p, int n) {
    int i = blockIdx.x * blockDim.x + threadIdx.x;
    for (; i < n; i += gridDim.x * blockDim.x) p[i] = 0u;
}

// Pass 1: per-anchor max/argmax/inside + per-gt column max
__global__ __launch_bounds__(256) void k_overlaps(
    const float4* __restrict__ anchors, const float4* __restrict__ gt,
    const float* __restrict__ iminfo, float* __restrict__ maxov,
    int* __restrict__ argm, unsigned char* __restrict__ insd,
    unsigned* __restrict__ gtm) {
    __shared__ float4 sg[NK];
    __shared__ float  sga[NK];
    __shared__ float  wmax[4][NK];
    int t = threadIdx.x;
    for (int k = t; k < NK; k += 256) {
        float4 g = gt[k];
        sg[k] = g;
        sga[k] = (g.z - g.x + 1.0f) * (g.w - g.y + 1.0f);
    }
    __syncthreads();
    int i = blockIdx.x * 256 + t;                 // NN == 900*256 exactly
    float4 a = anchors[i];
    float imh = iminfo[0], imw = iminfo[1];
    bool ins = (a.x >= 0.0f) && (a.y >= 0.0f) && (a.z < imw) && (a.w < imh);
    float ba = (a.z - a.x + 1.0f) * (a.w - a.y + 1.0f);
    float best = -INFINITY; int bidx = 0;
    int wid = t >> 6, lane = t & 63;
    for (int k = 0; k < NK; ++k) {
        float4 g = sg[k];
        float iw = fminf(a.z, g.z) - fmaxf(a.x, g.x) + 1.0f; iw = fmaxf(iw, 0.0f);
        float ih = fminf(a.w, g.w) - fmaxf(a.y, g.y) + 1.0f; ih = fmaxf(ih, 0.0f);
        float inter = iw * ih;
        float v = inter / (ba + sga[k] - inter);
        float ov = ins ? v : -1.0f;
        if (ov > best) { best = ov; bidx = k; }   // strict > => first max (matches jnp.argmax)
        float m = ov;
        #pragma unroll
        for (int off = 32; off > 0; off >>= 1) m = fmaxf(m, __shfl_xor(m, off, 64));
        if (lane == 0) wmax[wid][k] = m;
    }
    maxov[i] = best;
    argm[i]  = bidx;
    insd[i]  = ins ? 1 : 0;
    __syncthreads();
    if (t < NK) {
        float m = fmaxf(fmaxf(wmax[0][t], wmax[1][t]), fmaxf(wmax[2][t], wmax[3][t]));
        atomicMax(&gtm[t], encf(m));
    }
}

// Pass 2: labels (pre-subsample) + counts + hi-16 histograms of noise bits
__global__ __launch_bounds__(256) void k_labels(
    const float4* __restrict__ anchors, const float4* __restrict__ gt,
    const float* __restrict__ maxov, const unsigned char* __restrict__ insd,
    const unsigned* __restrict__ gtm, const float* __restrict__ noise,
    float* __restrict__ labels, unsigned* __restrict__ hfh,
    unsigned* __restrict__ hbh, unsigned* __restrict__ sc) {
    __shared__ float4 sg[NK];
    __shared__ float  sga[NK];
    __shared__ float  sgm[NK];
    int t = threadIdx.x;
    for (int k = t; k < NK; k += 256) {
        float4 g = gt[k];
        sg[k] = g;
        sga[k] = (g.z - g.x + 1.0f) * (g.w - g.y + 1.0f);
        sgm[k] = decf(gtm[k]);
    }
    __syncthreads();
    int i = blockIdx.x * 256 + t;
    float4 a = anchors[i];
    bool ins = insd[i] != 0;
    float ba = (a.z - a.x + 1.0f) * (a.w - a.y + 1.0f);
    bool gb = false;
    if (ins) {
        for (int k = 0; k < NK; ++k) {
            float4 g = sg[k];
            float iw = fminf(a.z, g.z) - fmaxf(a.x, g.x) + 1.0f; iw = fmaxf(iw, 0.0f);
            float ih = fminf(a.w, g.w) - fmaxf(a.y, g.y) + 1.0f; ih = fmaxf(ih, 0.0f);
            float inter = iw * ih;
            float v = inter / (ba + sga[k] - inter);
            gb = gb || (v == sgm[k]);             // exact equality, same rounding as pass 1
        }
    }
    float mo = maxov[i];
    float lab = -1.0f;
    if (ins && mo < 0.3f)  lab = 0.0f;
    if (ins && gb)         lab = 1.0f;
    if (ins && mo >= 0.7f) lab = 1.0f;
    labels[i] = lab;
    unsigned bits = __float_as_uint(noise[i]);
    if (lab == 1.0f)      { atomicAdd(&sc[S_CNT_FG], 1u); atomicAdd(&hfh[bits >> 16], 1u); }
    else if (lab == 0.0f) { atomicAdd(&sc[S_CNT_BG], 1u); atomicAdd(&hbh[bits >> 16], 1u); }
}

// hi-16 radix select: find bin containing k-th largest, remaining rank
__global__ __launch_bounds__(256) void k_scan_hi(
    const unsigned* __restrict__ hist, unsigned* __restrict__ sc, int isBg) {
    __shared__ unsigned csum[256];
    __shared__ unsigned suf[256];
    int t = threadIdx.x;
    unsigned k; int active;
    if (isBg) {
        int nfg = (int)sc[S_NFG_FINAL];
        int num_bg = 256 - nfg;
        int cnt = (int)sc[S_CNT_BG];
        active = cnt > num_bg;                    // matches: cnt > num_keep
        int kk = num_bg < 1 ? 1 : num_bg;         // matches idx = clip(num_keep-1, 0, N-1)
        k = (unsigned)kk;
        if (t == 0) { sc[S_BG_ACTIVE] = (unsigned)active; sc[S_BG_K] = k; }
    } else {
        unsigned cnt = sc[S_CNT_FG];
        active = cnt > 128u;
        k = 128u;
        if (t == 0) sc[S_FG_ACTIVE] = (unsigned)active;
    }
    if (!active) return;
    const unsigned* hp = hist + t * 256;
    unsigned s = 0;
    for (int b = 0; b < 256; ++b) s += hp[b];
    csum[t] = s;
    __syncthreads();
    if (t == 0) {
        unsigned run = 0;
        for (int c = 255; c >= 0; --c) { suf[c] = run; run += csum[c]; }
    }
    __syncthreads();
    unsigned above = suf[t];
    if (above < k && k <= above + csum[t]) {
        unsigned c = above;
        for (int b = 255; b >= 0; --b) {
            unsigned h = hp[b];
            c += h;
            if (c >= k) {
                if (isBg) { sc[S_BG_BIN] = (unsigned)(t * 256 + b); sc[S_BG_REM] = k - (c - h); }
                else      { sc[S_FG_BIN] = (unsigned)(t * 256 + b); sc[S_FG_REM] = k - (c - h); }
                break;
            }
        }
    }
}

// lo-16 histogram restricted to the selected hi bin
__global__ __launch_bounds__(256) void k_hist_lo(
    const float* __restrict__ labels, const float* __restrict__ noise,
    const unsigned* __restrict__ sc, unsigned* __restrict__ hist, int isBg) {
    if (!sc[isBg ? S_BG_ACTIVE : S_FG_ACTIVE]) return;
    unsigned hib = sc[isBg ? S_BG_BIN : S_FG_BIN];
    int i = blockIdx.x * 256 + threadIdx.x;
    float target = isBg ? 0.0f : 1.0f;
    if (labels[i] == target) {
        unsigned bits = __float_as_uint(noise[i]);
        if ((bits >> 16) == hib) atomicAdd(&hist[bits & 0xFFFFu], 1u);
    }
}

// lo-16 select -> exact threshold bits + kept count (handles ties like the reference)
__global__ __launch_bounds__(256) void k_scan_lo(
    const unsigned* __restrict__ hist, unsigned* __restrict__ sc, int isBg) {
    __shared__ unsigned csum[256];
    __shared__ unsigned suf[256];
    int t = threadIdx.x;
    unsigned active = sc[isBg ? S_BG_ACTIVE : S_FG_ACTIVE];
    if (!active) {
        if (t == 0) {
            if (!isBg) sc[S_NFG_FINAL] = sc[S_CNT_FG];
            else       sc[S_NUM_EX]    = sc[S_NFG_FINAL] + sc[S_CNT_BG];
        }
        return;
    }
    unsigned rem   = sc[isBg ? S_BG_REM : S_FG_REM];
    unsigned hib   = sc[isBg ? S_BG_BIN : S_FG_BIN];
    unsigned korig = isBg ? sc[S_BG_K] : 128u;
    const unsigned* hp = hist + t * 256;
    unsigned s = 0;
    for (int b = 0; b < 256; ++b) s += hp[b];
    csum[t] = s;
    __syncthreads();
    if (t == 0) {
        unsigned run = 0;
        for (int c = 255; c >= 0; --c) { suf[c] = run; run += csum[c]; }
    }
    __syncthreads();
    unsigned above = suf[t];
    if (above < rem && rem <= above + csum[t]) {
        unsigned c = above;
        for (int b = 255; b >= 0; --b) {
            unsigned h = hp[b];
            c += h;
            if (c >= rem) {
                unsigned th_bits = (hib << 16) | (unsigned)(t * 256 + b);
                unsigned nkept = (korig - rem) + c;   // count(noise >= th) among mask
                if (isBg) { sc[S_BG_TH] = th_bits; sc[S_NUM_EX] = sc[S_NFG_FINAL] + nkept; }
                else      { sc[S_FG_TH] = th_bits; sc[S_NFG_FINAL] = nkept; }
                break;
            }
        }
    }
}

// Final: apply disables, permuted label write, targets, weights
__global__ __launch_bounds__(256) void k_final(
    const float4* __restrict__ anchors, const float4* __restrict__ gt,
    const float* __restrict__ noise, const float* __restrict__ labels,
    const int* __restrict__ argm, const unsigned char* __restrict__ insd,
    const unsigned* __restrict__ sc,
    float* __restrict__ out0, float4* __restrict__ out1,
    float4* __restrict__ out2, float4* __restrict__ out3) {
    int i = blockIdx.x * 256 + threadIdx.x;
    unsigned fga = sc[S_FG_ACTIVE], bga = sc[S_BG_ACTIVE];
    float thf = __uint_as_float(sc[S_FG_TH]);
    float thb = __uint_as_float(sc[S_BG_TH]);

    // out0: dest-indexed permuted labels (coalesced store). dest i = a*HW + cell
    {
        int a0 = i / HW_, cell0 = i % HW_;
        int src = cell0 * NA + a0;
        float lab0 = labels[src];
        float nz0 = noise[src];
        if (fga && lab0 == 1.0f && nz0 < thf) lab0 = -1.0f;
        if (bga && lab0 == 0.0f && nz0 < thb) lab0 = -1.0f;
        out0[i] = lab0;
    }

    float lab = labels[i];
    float nz = noise[i];
    if (fga && lab == 1.0f && nz < thf) lab = -1.0f;
    if (bga && lab == 0.0f && nz < thb) lab = -1.0f;

    float4 an = anchors[i];
    float4 g = gt[argm[i]];
    float ew = an.z - an.x + 1.0f, eh = an.w - an.y + 1.0f;
    float ecx = an.x + 0.5f * ew,  ecy = an.y + 0.5f * eh;
    float gw = g.z - g.x + 1.0f,   gh = g.w - g.y + 1.0f;
    float gcx = g.x + 0.5f * gw,   gcy = g.y + 0.5f * gh;
    float t0 = (gcx - ecx) / ew;
    float t1 = (gcy - ecy) / eh;
    float t2 = logf(gw / ew);
    float t3 = logf(gh / eh);
    if (insd[i] == 0) { t0 = 0.0f; t1 = 0.0f; t2 = 0.0f; t3 = 0.0f; }
    out1[i] = make_float4(t0, t1, t2, t3);

    float biw = (lab == 1.0f) ? 1.0f : 0.0f;
    out2[i] = make_float4(biw, biw, biw, biw);

    float inv = 1.0f / (float)sc[S_NUM_EX];
    float bow = (lab >= 0.0f) ? inv : 0.0f;
    out3[i] = make_float4(bow, bow, bow, bow);
}

extern "C" void kernel_launch(void* const* d_in, const int* in_sizes, int n_in,
                              void* d_out, int out_size, void* d_ws, size_t ws_size,
                              hipStream_t stream) {
    const float4* anchors = (const float4*)d_in[0];
    const float4* gt      = (const float4*)d_in[1];
    const float*  iminfo  = (const float*)d_in[2];
    const float*  noise   = (const float*)d_in[3];

    float*  out0 = (float*)d_out;                  // NN
    float4* out1 = (float4*)(out0 + NN);           // NN x 4
    float4* out2 = (float4*)(out0 + NN + 4 * NN);  // NN x 4
    float4* out3 = (float4*)(out0 + NN + 8 * NN);  // NN x 4

    char* ws = (char*)d_ws;
    unsigned* sc  = (unsigned*)ws;                          // 64 u32
    unsigned* gtm = (unsigned*)(ws + 256);                  // 128 u32
    unsigned* hfh = (unsigned*)(ws + 1024);                 // 65536 u32
    unsigned* hfl = hfh + 65536;
    unsigned* hbh = hfl + 65536;
    unsigned* hbl = hbh + 65536;
    float* labels = (float*)(ws + 1049600);                 // NN f32
    float* maxov  = labels + NN;                            // NN f32
    int*   argm   = (int*)(maxov + NN);                     // NN i32
    unsigned char* insd = (unsigned char*)(argm + NN);      // NN u8

    // zero scalars + gt_max + 4 histograms = 262400 u32
    k_init<<<256, 256, 0, stream>>>((unsigned*)ws, 262400);
    k_overlaps<<<NBLK, 256, 0, stream>>>(anchors, gt, iminfo, maxov, argm, insd, gtm);
    k_labels<<<NBLK, 256, 0, stream>>>(anchors, gt, maxov, insd, gtm, noise, labels, hfh, hbh, sc);
    k_scan_hi<<<1, 256, 0, stream>>>(hfh, sc, 0);
    k_hist_lo<<<NBLK, 256, 0, stream>>>(labels, noise, sc, hfl, 0);
    k_scan_lo<<<1, 256, 0, stream>>>(hfl, sc, 0);
    k_scan_hi<<<1, 256, 0, stream>>>(hbh, sc, 1);
    k_hist_lo<<<NBLK, 256, 0, stream>>>(labels, noise, sc, hbl, 1);
    k_scan_lo<<<1, 256, 0, stream>>>(hbl, sc, 1);
    k_final<<<NBLK, 256, 0, stream>>>(anchors, gt, noise, labels, argm, insd, sc,
                                      out0, out1, out2, out3);
}

// Round 2
// 245.001 us; speedup vs baseline: 1.0677x; 1.0677x over previous
//
#include <hip/hip_runtime.h>
#include <hip/hip_bf16.h>

#pragma clang fp contract(off)

#define NN   230400   // H*W*A
#define NK   128      // gt boxes
#define HW_  25600    // H*W
#define NA   9
#define NBLK 900      // NN/256

// ---- scalar slots in ws ----
enum { S_CNT_FG=0, S_CNT_BG, S_FG_ACTIVE, S_FG_BIN, S_FG_REM, S_FG_TH, S_NFG_FINAL,
       S_BG_ACTIVE, S_BG_BIN, S_BG_REM, S_BG_TH, S_BG_K, S_NUM_EX };

__device__ __forceinline__ unsigned encf(float f) {
    unsigned u = __float_as_uint(f);
    return (u & 0x80000000u) ? ~u : (u | 0x80000000u);
}
__device__ __forceinline__ float decf(unsigned e) {
    unsigned u = (e & 0x80000000u) ? (e & 0x7FFFFFFFu) : ~e;
    return __uint_as_float(u);
}

__global__ __launch_bounds__(256) void k_init(unsigned* __restrict__ p, int n) {
    int i = blockIdx.x * blockDim.x + threadIdx.x;
    for (; i < n; i += gridDim.x * blockDim.x) p[i] = 0u;
}

// Pass 1: K split 4-ways. Block = 64 anchors x 4 k-groups of 32. 3600 blocks.
__global__ __launch_bounds__(256) void k_overlaps(
    const float4* __restrict__ anchors, const float4* __restrict__ gt,
    const float* __restrict__ iminfo, float* __restrict__ maxov,
    int* __restrict__ argm, unsigned char* __restrict__ insd,
    unsigned* __restrict__ gtm) {
    __shared__ float4 sg[NK];
    __shared__ float  sga[NK];
    __shared__ float  wsm[NK];          // per-block column max
    __shared__ float  sbest[4][64];
    __shared__ int    sbidx[4][64];
    int t = threadIdx.x;
    if (t < NK) {
        float4 g = gt[t];
        sg[t] = g;
        sga[t] = (g.z - g.x + 1.0f) * (g.w - g.y + 1.0f);
    }
    __syncthreads();
    int lane = t & 63, wid = t >> 6;
    int i = blockIdx.x * 64 + lane;
    float4 a = anchors[i];
    float imh = iminfo[0], imw = iminfo[1];
    bool ins = (a.x >= 0.0f) && (a.y >= 0.0f) && (a.z < imw) && (a.w < imh);
    float ba = (a.z - a.x + 1.0f) * (a.w - a.y + 1.0f);
    float best = -INFINITY; int bidx = 0;
    int k0 = wid * 32;
    for (int kk = 0; kk < 32; ++kk) {
        int k = k0 + kk;
        float4 g = sg[k];
        float iw = fminf(a.z, g.z) - fmaxf(a.x, g.x) + 1.0f; iw = fmaxf(iw, 0.0f);
        float ih = fminf(a.w, g.w) - fmaxf(a.y, g.y) + 1.0f; ih = fmaxf(ih, 0.0f);
        float inter = iw * ih;
        float v = inter / (ba + sga[k] - inter);
        float ov = ins ? v : -1.0f;
        if (ov > best) { best = ov; bidx = k; }   // strict > => first max within group
        float m = ov;
        #pragma unroll
        for (int off = 32; off > 0; off >>= 1) m = fmaxf(m, __shfl_xor(m, off, 64));
        if (lane == 0) wsm[k] = m;
    }
    sbest[wid][lane] = best;
    sbidx[wid][lane] = bidx;
    __syncthreads();
    if (wid == 0) {
        float b = sbest[0][lane]; int bi = sbidx[0][lane];
        #pragma unroll
        for (int w = 1; w < 4; ++w) {
            float b2 = sbest[w][lane];
            if (b2 > b) { b = b2; bi = sbidx[w][lane]; }  // ascending k-groups + strict > => first max
        }
        maxov[i] = b;
        argm[i]  = bi;
        insd[i]  = ins ? 1 : 0;
    }
    if (t < NK) {
        unsigned e = encf(wsm[t]);
        if (e > gtm[t]) atomicMax(&gtm[t], e);   // racy prefilter; atomic is authoritative
    }
}

// Sort columns ascending by gt_max (ties by index). O(128^2) rank sort, 1 block.
__global__ __launch_bounds__(128) void k_sortgt(
    const float4* __restrict__ gt, const unsigned* __restrict__ gtm,
    float4* __restrict__ sgt, float* __restrict__ sgar, float* __restrict__ sgmv) {
    __shared__ unsigned se[NK];
    int t = threadIdx.x;
    unsigned e = gtm[t];
    se[t] = e;
    __syncthreads();
    int rank = 0;
    for (int j = 0; j < NK; ++j) {
        unsigned ej = se[j];
        rank += (ej < e) || (ej == e && j < t);
    }
    float4 g = gt[t];
    sgt[rank]  = g;
    sgar[rank] = (g.z - g.x + 1.0f) * (g.w - g.y + 1.0f);
    sgmv[rank] = decf(e);
}

// Pass 2: labels via pruned column scan (break when gt_max > max_ov)
__global__ __launch_bounds__(256) void k_labels(
    const float4* __restrict__ anchors, const float4* __restrict__ sgtb,
    const float* __restrict__ sgab, const float* __restrict__ sgmb,
    const float* __restrict__ maxov, const unsigned char* __restrict__ insd,
    const float* __restrict__ noise,
    float* __restrict__ labels, unsigned* __restrict__ hfh,
    unsigned* __restrict__ hbh, unsigned* __restrict__ sc) {
    __shared__ float4 sg[NK];
    __shared__ float  sga[NK];
    __shared__ float  sgm[NK];
    int t = threadIdx.x;
    if (t < NK) {
        sg[t]  = sgtb[t];
        sga[t] = sgab[t];
        sgm[t] = sgmb[t];
    }
    __syncthreads();
    int i = blockIdx.x * 256 + t;
    bool ins = insd[i] != 0;
    float mo = maxov[i];
    bool gb = false;
    if (ins) {
        float4 a = anchors[i];
        float ba = (a.z - a.x + 1.0f) * (a.w - a.y + 1.0f);
        for (int j = 0; j < NK; ++j) {
            float gm = sgm[j];
            if (gm > mo) break;                   // ov[i][k] <= mo < gt_max[k]: can't match
            float4 g = sg[j];
            float iw = fminf(a.z, g.z) - fmaxf(a.x, g.x) + 1.0f; iw = fmaxf(iw, 0.0f);
            float ih = fminf(a.w, g.w) - fmaxf(a.y, g.y) + 1.0f; ih = fmaxf(ih, 0.0f);
            float inter = iw * ih;
            float v = inter / (ba + sga[j] - inter);
            gb = gb || (v == gm);                 // exact equality, same rounding as pass 1
        }
    }
    float lab = -1.0f;
    if (ins && mo < 0.3f)  lab = 0.0f;
    if (ins && gb)         lab = 1.0f;
    if (ins && mo >= 0.7f) lab = 1.0f;
    labels[i] = lab;
    unsigned bits = __float_as_uint(noise[i]);
    if (lab == 1.0f)      { atomicAdd(&sc[S_CNT_FG], 1u); atomicAdd(&hfh[bits >> 16], 1u); }
    else if (lab == 0.0f) { atomicAdd(&sc[S_CNT_BG], 1u); atomicAdd(&hbh[bits >> 16], 1u); }
}

// hi-16 radix select for fg: find bin containing 128th largest, remaining rank
__global__ __launch_bounds__(256) void k_scan_hi_fg(
    const unsigned* __restrict__ hist, unsigned* __restrict__ sc) {
    __shared__ unsigned csum[256];
    __shared__ unsigned suf[256];
    int t = threadIdx.x;
    unsigned cnt = sc[S_CNT_FG];
    int active = cnt > 128u;
    if (t == 0) sc[S_FG_ACTIVE] = (unsigned)active;
    if (!active) return;
    const unsigned k = 128u;
    const unsigned* hp = hist + t * 256;
    unsigned s = 0;
    for (int b = 0; b < 256; ++b) s += hp[b];
    csum[t] = s;
    __syncthreads();
    if (t == 0) {
        unsigned run = 0;
        for (int c = 255; c >= 0; --c) { suf[c] = run; run += csum[c]; }
    }
    __syncthreads();
    unsigned above = suf[t];
    if (above < k && k <= above + csum[t]) {
        unsigned c = above;
        for (int b = 255; b >= 0; --b) {
            unsigned h = hp[b];
            c += h;
            if (c >= k) { sc[S_FG_BIN] = (unsigned)(t * 256 + b); sc[S_FG_REM] = k - (c - h); break; }
        }
    }
}

// lo-16 histogram restricted to the selected hi bin
__global__ __launch_bounds__(256) void k_hist_lo(
    const float* __restrict__ labels, const float* __restrict__ noise,
    const unsigned* __restrict__ sc, unsigned* __restrict__ hist, int isBg) {
    if (!sc[isBg ? S_BG_ACTIVE : S_FG_ACTIVE]) return;
    unsigned hib = sc[isBg ? S_BG_BIN : S_FG_BIN];
    int i = blockIdx.x * 256 + threadIdx.x;
    float target = isBg ? 0.0f : 1.0f;
    if (labels[i] == target) {
        unsigned bits = __float_as_uint(noise[i]);
        if ((bits >> 16) == hib) atomicAdd(&hist[bits & 0xFFFFu], 1u);
    }
}

// merged: lo-16 select for fg  ->  hi-16 select for bg (nfg via shared mem)
__global__ __launch_bounds__(256) void k_mid(
    const unsigned* __restrict__ hfl, const unsigned* __restrict__ hbh,
    unsigned* __restrict__ sc) {
    __shared__ unsigned csum[256];
    __shared__ unsigned suf[256];
    __shared__ unsigned snfg;
    int t = threadIdx.x;
    unsigned factive = sc[S_FG_ACTIVE];
    if (!factive) {
        if (t == 0) snfg = sc[S_CNT_FG];
    } else {
        unsigned rem = sc[S_FG_REM];
        unsigned hib = sc[S_FG_BIN];
        const unsigned* hp = hfl + t * 256;
        unsigned s = 0;
        for (int b = 0; b < 256; ++b) s += hp[b];
        csum[t] = s;
        __syncthreads();
        if (t == 0) {
            unsigned run = 0;
            for (int c = 255; c >= 0; --c) { suf[c] = run; run += csum[c]; }
        }
        __syncthreads();
        unsigned above = suf[t];
        if (above < rem && rem <= above + csum[t]) {
            unsigned c = above;
            for (int b = 255; b >= 0; --b) {
                unsigned h = hp[b];
                c += h;
                if (c >= rem) {
                    sc[S_FG_TH] = (hib << 16) | (unsigned)(t * 256 + b);
                    snfg = (128u - rem) + c;       // count(noise >= th) among fg
                    break;
                }
            }
        }
    }
    __syncthreads();
    // ---- bg hi-16 select ----
    int nfg = (int)snfg;
    int num_bg = 256 - nfg;
    int cnt = (int)sc[S_CNT_BG];
    int bactive = cnt > num_bg;
    int kk = num_bg < 1 ? 1 : num_bg;
    unsigned k = (unsigned)kk;
    if (t == 0) { sc[S_BG_ACTIVE] = (unsigned)bactive; sc[S_BG_K] = k; sc[S_NFG_FINAL] = (unsigned)nfg; }
    if (!bactive) return;
    const unsigned* hp = hbh + t * 256;
    unsigned s = 0;
    for (int b = 0; b < 256; ++b) s += hp[b];
    csum[t] = s;
    __syncthreads();
    if (t == 0) {
        unsigned run = 0;
        for (int c = 255; c >= 0; --c) { suf[c] = run; run += csum[c]; }
    }
    __syncthreads();
    unsigned above = suf[t];
    if (above < k && k <= above + csum[t]) {
        unsigned c = above;
        for (int b = 255; b >= 0; --b) {
            unsigned h = hp[b];
            c += h;
            if (c >= k) { sc[S_BG_BIN] = (unsigned)(t * 256 + b); sc[S_BG_REM] = k - (c - h); break; }
        }
    }
}

// lo-16 select for bg -> exact threshold bits + S_NUM_EX
__global__ __launch_bounds__(256) void k_scan_lo_bg(
    const unsigned* __restrict__ hist, unsigned* __restrict__ sc) {
    __shared__ unsigned csum[256];
    __shared__ unsigned suf[256];
    int t = threadIdx.x;
    unsigned active = sc[S_BG_ACTIVE];
    if (!active) {
        if (t == 0) sc[S_NUM_EX] = sc[S_NFG_FINAL] + sc[S_CNT_BG];
        return;
    }
    unsigned rem   = sc[S_BG_REM];
    unsigned hib   = sc[S_BG_BIN];
    unsigned korig = sc[S_BG_K];
    const unsigned* hp = hist + t * 256;
    unsigned s = 0;
    for (int b = 0; b < 256; ++b) s += hp[b];
    csum[t] = s;
    __syncthreads();
    if (t == 0) {
        unsigned run = 0;
        for (int c = 255; c >= 0; --c) { suf[c] = run; run += csum[c]; }
    }
    __syncthreads();
    unsigned above = suf[t];
    if (above < rem && rem <= above + csum[t]) {
        unsigned c = above;
        for (int b = 255; b >= 0; --b) {
            unsigned h = hp[b];
            c += h;
            if (c >= rem) {
                sc[S_BG_TH] = (hib << 16) | (unsigned)(t * 256 + b);
                sc[S_NUM_EX] = sc[S_NFG_FINAL] + ((korig - rem) + c);
                break;
            }
        }
    }
}

// Final: apply disables, permuted label write, targets, weights
__global__ __launch_bounds__(256) void k_final(
    const float4* __restrict__ anchors, const float4* __restrict__ gt,
    const float* __restrict__ noise, const float* __restrict__ labels,
    const int* __restrict__ argm, const unsigned char* __restrict__ insd,
    const unsigned* __restrict__ sc,
    float* __restrict__ out0, float4* __restrict__ out1,
    float4* __restrict__ out2, float4* __restrict__ out3) {
    int i = blockIdx.x * 256 + threadIdx.x;
    unsigned fga = sc[S_FG_ACTIVE], bga = sc[S_BG_ACTIVE];
    float thf = __uint_as_float(sc[S_FG_TH]);
    float thb = __uint_as_float(sc[S_BG_TH]);

    // out0: dest-indexed permuted labels. dest i = a*HW + cell; src = cell*NA + a
    {
        int a0 = i / HW_, cell0 = i % HW_;
        int src = cell0 * NA + a0;
        float lab0 = labels[src];
        float nz0 = noise[src];
        if (fga && lab0 == 1.0f && nz0 < thf) lab0 = -1.0f;
        if (bga && lab0 == 0.0f && nz0 < thb) lab0 = -1.0f;
        out0[i] = lab0;
    }

    float lab = labels[i];
    float nz = noise[i];
    if (fga && lab == 1.0f && nz < thf) lab = -1.0f;
    if (bga && lab == 0.0f && nz < thb) lab = -1.0f;

    float4 an = anchors[i];
    float4 g = gt[argm[i]];
    float ew = an.z - an.x + 1.0f, eh = an.w - an.y + 1.0f;
    float ecx = an.x + 0.5f * ew,  ecy = an.y + 0.5f * eh;
    float gw = g.z - g.x + 1.0f,   gh = g.w - g.y + 1.0f;
    float gcx = g.x + 0.5f * gw,   gcy = g.y + 0.5f * gh;
    float t0 = (gcx - ecx) / ew;
    float t1 = (gcy - ecy) / eh;
    float t2 = logf(gw / ew);
    float t3 = logf(gh / eh);
    if (insd[i] == 0) { t0 = 0.0f; t1 = 0.0f; t2 = 0.0f; t3 = 0.0f; }
    out1[i] = make_float4(t0, t1, t2, t3);

    float biw = (lab == 1.0f) ? 1.0f : 0.0f;
    out2[i] = make_float4(biw, biw, biw, biw);

    float inv = 1.0f / (float)sc[S_NUM_EX];
    float bow = (lab >= 0.0f) ? inv : 0.0f;
    out3[i] = make_float4(bow, bow, bow, bow);
}

extern "C" void kernel_launch(void* const* d_in, const int* in_sizes, int n_in,
                              void* d_out, int out_size, void* d_ws, size_t ws_size,
                              hipStream_t stream) {
    const float4* anchors = (const float4*)d_in[0];
    const float4* gt      = (const float4*)d_in[1];
    const float*  iminfo  = (const float*)d_in[2];
    const float*  noise   = (const float*)d_in[3];

    float*  out0 = (float*)d_out;                  // NN
    float4* out1 = (float4*)(out0 + NN);           // NN x 4
    float4* out2 = (float4*)(out0 + NN + 4 * NN);  // NN x 4
    float4* out3 = (float4*)(out0 + NN + 8 * NN);  // NN x 4

    char* ws = (char*)d_ws;
    unsigned* sc   = (unsigned*)ws;                         // 64 u32
    unsigned* gtm  = (unsigned*)(ws + 256);                 // 128 u32
    float*    sgmv = (float*)(ws + 768);                    // 128 f32 (sorted gt_max)
    float*    sgar = (float*)(ws + 1280);                   // 128 f32 (sorted areas)
    float4*   sgt  = (float4*)(ws + 1792);                  // 128 f4  (sorted boxes)
    unsigned* hfh  = (unsigned*)(ws + 4096);                // 65536 u32
    unsigned* hfl  = hfh + 65536;
    unsigned* hbh  = hfl + 65536;
    unsigned* hbl  = hbh + 65536;
    float* labels  = (float*)(ws + 4096 + 4 * 262144);      // NN f32
    float* maxov   = labels + NN;                           // NN f32
    int*   argm    = (int*)(maxov + NN);                    // NN i32
    unsigned char* insd = (unsigned char*)(argm + NN);      // NN u8

    // zero: sc + gtm + sorted + 4 histograms (first 4096+1MB bytes)
    k_init<<<256, 256, 0, stream>>>((unsigned*)ws, (4096 + 4 * 262144 * 4) / 4);
    k_overlaps<<<3600, 256, 0, stream>>>(anchors, gt, iminfo, maxov, argm, insd, gtm);
    k_sortgt<<<1, 128, 0, stream>>>(gt, gtm, sgt, sgar, sgmv);
    k_labels<<<NBLK, 256, 0, stream>>>(anchors, sgt, sgar, sgmv, maxov, insd, noise,
                                       labels, hfh, hbh, sc);
    k_scan_hi_fg<<<1, 256, 0, stream>>>(hfh, sc);
    k_hist_lo<<<NBLK, 256, 0, stream>>>(labels, noise, sc, hfl, 0);
    k_mid<<<1, 256, 0, stream>>>(hfl, hbh, sc);
    k_hist_lo<<<NBLK, 256, 0, stream>>>(labels, noise, sc, hbl, 1);
    k_scan_lo_bg<<<1, 256, 0, stream>>>(hbl, sc);
    k_final<<<NBLK, 256, 0, stream>>>(anchors, gt, noise, labels, argm, insd, sc,
                                      out0, out1, out2, out3);
}